// Round 20
// baseline (166.566 us; speedup 1.0000x reference)
//
#include <hip/hip_runtime.h>
#include <hip/hip_bf16.h>
#include <hip/hip_fp16.h>

#define TOKENS 22506
#define SLEN   11253

typedef __bf16 bf16x8 __attribute__((ext_vector_type(8)));
typedef float  f32x4  __attribute__((ext_vector_type(4)));
typedef float  f32x2  __attribute__((ext_vector_type(2)));
typedef uint   u32x4  __attribute__((ext_vector_type(4)));
typedef uint   u32x2  __attribute__((ext_vector_type(2)));

#if defined(__has_builtin)
#if __has_builtin(__builtin_amdgcn_cvt_pk_f32_fp8) && __has_builtin(__builtin_amdgcn_cvt_pk_fp8_f32)
#define HAS_FP8CVT 1
#endif
#endif

__device__ __forceinline__ ushort f2bu(float f) {
    __hip_bfloat16 h = __float2bfloat16(f);   // RNE
    return *reinterpret_cast<ushort*>(&h);
}
__device__ __forceinline__ float bu2f(ushort u) {
    return __uint_as_float((uint)u << 16);
}
__device__ __forceinline__ uint pkf16(float a, float b) {
    __half2 h = __floats2half2_rn(a, b);
    return *reinterpret_cast<uint*>(&h);
}
__device__ __forceinline__ void gl16(const void* g, void* l) {
    __builtin_amdgcn_global_load_lds(
        (__attribute__((address_space(1))) void*)(g),
        (__attribute__((address_space(3))) void*)(l), 16, 0, 0);
}

#ifndef HAS_FP8CVT
// fallback software e4m3fn codec (compile-safety only)
__device__ __forceinline__ uint enc_fp8(float x) {
    if (!(fabsf(x) >= 0.f)) return 0;
    uint u = __float_as_uint(x);
    uint s = (u >> 24) & 0x80u;
    float ax = fabsf(x);
    if (ax >= 448.f) return s | 0x7Eu;
    if (ax < 0.0009765625f) return s;
    int e; frexpf(ax, &e);
    int ue = e - 1;
    if (ue < -6) {
        int m = (int)(ax * 512.f + 0.5f);
        if (m > 7) m = 7;
        return s | (uint)m;
    }
    float q = ax * exp2f((float)(3 - ue));
    int mi = (int)(q + 0.5f);
    if (mi >= 16) { mi >>= 1; ++ue; if (ue > 8) return s | 0x7Eu; }
    return s | ((uint)(ue + 7) << 3) | ((uint)mi & 7u);
}
__device__ __forceinline__ float dec_fp8(uint b) {
    const float sgn = (b & 0x80u) ? -1.f : 1.f;
    const uint e = (b >> 3) & 15u, m = b & 7u;
    if (e == 0) return sgn * (float)m * 0.001953125f;
    return sgn * (1.0f + (float)m * 0.125f) * exp2f((float)e - 7.f);
}
#endif

__device__ __forceinline__ uint fp8pack4(float f0, float f1, float f2, float f3) {
#ifdef HAS_FP8CVT
    int p = 0;
    p = __builtin_amdgcn_cvt_pk_fp8_f32(f0, f1, p, false);
    p = __builtin_amdgcn_cvt_pk_fp8_f32(f2, f3, p, true);
    return (uint)p;
#else
    return enc_fp8(f0) | (enc_fp8(f1) << 8) | (enc_fp8(f2) << 16) | (enc_fp8(f3) << 24);
#endif
}
__device__ __forceinline__ uint fp8pack1(float f) {
#ifdef HAS_FP8CVT
    return (uint)__builtin_amdgcn_cvt_pk_fp8_f32(f, f, 0, false) & 0xFFu;
#else
    return enc_fp8(f);
#endif
}
template<bool HI>
__device__ __forceinline__ f32x2 fp8pair(uint w) {
#ifdef HAS_FP8CVT
    auto c = __builtin_amdgcn_cvt_pk_f32_fp8((int)w, HI);   // HI is a literal
    f32x2 r; r.x = c[0]; r.y = c[1]; return r;
#else
    const uint sh = HI ? 16u : 0u;
    f32x2 r; r.x = dec_fp8((w >> sh) & 0xFFu); r.y = dec_fp8((w >> (sh + 8)) & 0xFFu);
    return r;
#endif
}

// XCD row-partition swizzle (bijective when nx % 8 == 0); perf heuristic.
__device__ __forceinline__ void xcd_swz(int& bx, int& by) {
    const int nx = gridDim.x, ny = gridDim.y;
    if ((nx & 7) == 0) {
        const int L = blockIdx.x + nx * blockIdx.y;
        const int chunk = nx >> 3;
        const int k = L & 7, j = L >> 3;
        bx = k * chunk + (j % chunk);
        by = j / chunk;
        if (by >= ny) { bx = blockIdx.x; by = blockIdx.y; }  // safety
    } else {
        bx = blockIdx.x; by = blockIdx.y;
    }
}

// ---------------------------------------------------------------------------
// 64x128-tile MFMA GEMM (bf16 inputs).
// F8MODE: 0 = bf16 C; 1 = fp8 C row-major (lin1 h); 2 = z==0 slice fp8 C in
// per-head TRANSPOSED layout valT[(b*8+head)*SLEN+s][32] (value; N==256).
// ---------------------------------------------------------------------------
template<bool RELU, bool NTSTORE, int F8MODE>
__global__ __launch_bounds__(256) void gemm_small(
    const ushort* __restrict__ A0, const ushort* __restrict__ W0,
    const float* __restrict__ b0, void* __restrict__ C0,
    const ushort* __restrict__ A1, const ushort* __restrict__ W1,
    const float* __restrict__ b1, void* __restrict__ C1,
    int M, int N, int K)
{
    const bool zz = blockIdx.z != 0;
    const ushort* A   = zz ? A1 : A0;
    const ushort* W   = zz ? W1 : W0;
    const float* bias = zz ? b1 : b0;
    void* Cptr        = zz ? C1 : C0;

    __shared__ ushort smem[12288];           // 24 KB
    const int tid  = threadIdx.x;
    const int lane = tid & 63;
    const int wid  = tid >> 6;
    const int wr = wid >> 1, wc = wid & 1;
    int bx, by; xcd_swz(bx, by);
    const int m0 = bx * 64, n0 = by * 128;
    const int lrow = lane & 15, lhi = lane >> 4;

    const int arow = tid >> 2;               // 0..63
    const int scol = (tid & 3) << 3;
    const ushort* ga  = A + (size_t)min(m0 + arow, M - 1) * K + scol;
    const ushort* gb0 = W + (size_t)(n0 + arow)      * K + scol;
    const ushort* gb1 = W + (size_t)(n0 + arow + 64) * K + scol;

    f32x4 acc[2][4] = {};
    const int NT = K >> 5;

    gl16(ga,  &smem[tid * 8]);
    gl16(gb0, &smem[4096 + tid * 8]);
    gl16(gb1, &smem[4096 + tid * 8 + 2048]);

    int cur = 0;
    for (int t = 0; t < NT; ++t) {
        __syncthreads();
        if (t + 1 < NT) {
            const int k0 = (t + 1) << 5;
            const int nb = cur ^ 1;
            gl16(ga  + k0, &smem[nb * 2048 + tid * 8]);
            gl16(gb0 + k0, &smem[4096 + nb * 4096 + tid * 8]);
            gl16(gb1 + k0, &smem[4096 + nb * 4096 + tid * 8 + 2048]);
        }
        bf16x8 afr[2], bfr[4];
        #pragma unroll
        for (int m = 0; m < 2; ++m)
            afr[m] = *reinterpret_cast<const bf16x8*>(
                &smem[cur * 2048 + (wr * 32 + m * 16 + lrow) * 32 + lhi * 8]);
        #pragma unroll
        for (int n = 0; n < 4; ++n)
            bfr[n] = *reinterpret_cast<const bf16x8*>(
                &smem[4096 + cur * 4096 + (wc * 64 + n * 16 + lrow) * 32 + lhi * 8]);
        #pragma unroll
        for (int m = 0; m < 2; ++m)
            #pragma unroll
            for (int n = 0; n < 4; ++n)
                acc[m][n] = __builtin_amdgcn_mfma_f32_16x16x32_bf16(
                    afr[m], bfr[n], acc[m][n], 0, 0, 0);
        cur ^= 1;
    }

    // epilogue: regs -> LDS (padded 136-elem rows) -> coalesced stores
    __syncthreads();
    #pragma unroll
    for (int m = 0; m < 2; ++m) {
        #pragma unroll
        for (int n = 0; n < 4; ++n) {
            const int col = wc * 64 + n * 16 + lrow;
            const float bv = bias[n0 + col];
            #pragma unroll
            for (int r = 0; r < 4; ++r) {
                const int row = wr * 32 + m * 16 + lhi * 4 + r;
                float v = acc[m][n][r] + bv;
                if (RELU) v = fmaxf(v, 0.f);
                smem[row * 136 + col] = f2bu(v);
            }
        }
    }
    __syncthreads();
    if (F8MODE != 0 && (F8MODE == 1 || !zz)) {
        #pragma unroll
        for (int i = 0; i < 4; ++i) {
            const int e = tid + i * 256;
            const int row = e >> 4, ch = e & 15;
            const int grow = m0 + row;
            if (grow < M) {
                const u32x4 v = *reinterpret_cast<const u32x4*>(&smem[row * 136 + ch * 8]);
                float f[8];
                #pragma unroll
                for (int j = 0; j < 4; ++j) {
                    f[2 * j]     = __uint_as_float(v[j] << 16);
                    f[2 * j + 1] = __uint_as_float(v[j] & 0xFFFF0000u);
                }
                u32x2 o;
                o[0] = fp8pack4(f[0], f[1], f[2], f[3]);
                o[1] = fp8pack4(f[4], f[5], f[6], f[7]);
                if (F8MODE == 2) {
                    // transposed per-head value write
                    const int b = grow >= SLEN;
                    const int s = grow - (b ? SLEN : 0);
                    const int head = (n0 >> 5) + (ch >> 2);
                    const int d0 = (ch & 3) * 8;
                    *reinterpret_cast<u32x2*>(
                        (unsigned char*)Cptr +
                        ((size_t)(b * 8 + head) * SLEN + s) * 32 + d0) = o;
                } else {
                    u32x2* dst = reinterpret_cast<u32x2*>(
                        (unsigned char*)Cptr + (size_t)grow * N + n0 + ch * 8);
                    if (NTSTORE) __builtin_nontemporal_store(o, dst);
                    else *dst = o;
                }
            }
        }
    } else {
        #pragma unroll
        for (int i = 0; i < 4; ++i) {
            const int e = tid + i * 256;
            const int row = e >> 4, ch = e & 15;
            if (m0 + row < M) {
                const u32x4 v = *reinterpret_cast<const u32x4*>(&smem[row * 136 + ch * 8]);
                u32x4* dst = reinterpret_cast<u32x4*>(
                    (ushort*)Cptr + (size_t)(m0 + row) * N + n0 + ch * 8);
                if (NTSTORE) __builtin_nontemporal_store(v, dst);
                else *dst = v;
            }
        }
    }
}

// ---------------------------------------------------------------------------
// 64x128-tile MFMA GEMM, fp8-e4m3 A and W (lin2).
// ---------------------------------------------------------------------------
__global__ __launch_bounds__(256) void gemm_f8(
    const unsigned char* __restrict__ A, const unsigned char* __restrict__ W,
    const float* __restrict__ bias, ushort* __restrict__ C,
    int M, int N, int K)
{
    __shared__ unsigned char smem[17408];    // staging 12 KB; epilogue 17.4 KB
    const int tid  = threadIdx.x;
    const int lane = tid & 63;
    const int wid  = tid >> 6;
    const int wr = wid >> 1, wc = wid & 1;
    int bx, by; xcd_swz(bx, by);
    const int m0 = bx * 64, n0 = by * 128;
    const int lrow = lane & 15, lhi = lane >> 4;

    const int arow = tid >> 1;               // 0..127
    const int achk = (tid & 1) << 4;         // 0 or 16 (bytes)
    const unsigned char* ga = A + (size_t)min(m0 + (arow & 63), M - 1) * K + achk;
    const unsigned char* gb = W + (size_t)(n0 + arow) * K + achk;

    f32x4 acc[2][4] = {};
    const int NT = K >> 5;

    if (tid < 128) gl16(ga, &smem[tid * 16]);
    gl16(gb, &smem[4096 + tid * 16]);

    int cur = 0;
    for (int t = 0; t < NT; ++t) {
        __syncthreads();
        if (t + 1 < NT) {
            const int k0 = (t + 1) << 5;
            const int nb = cur ^ 1;
            if (tid < 128) gl16(ga + k0, &smem[nb * 2048 + tid * 16]);
            gl16(gb + k0, &smem[4096 + nb * 4096 + tid * 16]);
        }
        long afr[2], bfr[4];
        #pragma unroll
        for (int m = 0; m < 2; ++m)
            afr[m] = *reinterpret_cast<const long*>(
                &smem[cur * 2048 + (wr * 32 + m * 16 + lrow) * 32 + lhi * 8]);
        #pragma unroll
        for (int n = 0; n < 4; ++n)
            bfr[n] = *reinterpret_cast<const long*>(
                &smem[4096 + cur * 4096 + (wc * 64 + n * 16 + lrow) * 32 + lhi * 8]);
        #pragma unroll
        for (int m = 0; m < 2; ++m)
            #pragma unroll
            for (int n = 0; n < 4; ++n)
                acc[m][n] = __builtin_amdgcn_mfma_f32_16x16x32_fp8_fp8(
                    afr[m], bfr[n], acc[m][n], 0, 0, 0);
        cur ^= 1;
    }

    __syncthreads();
    ushort* sm16 = reinterpret_cast<ushort*>(smem);
    #pragma unroll
    for (int m = 0; m < 2; ++m) {
        #pragma unroll
        for (int n = 0; n < 4; ++n) {
            const int col = wc * 64 + n * 16 + lrow;
            const float bv = bias[n0 + col];
            #pragma unroll
            for (int r = 0; r < 4; ++r) {
                const int row = wr * 32 + m * 16 + lhi * 4 + r;
                sm16[row * 136 + col] = f2bu(acc[m][n][r] + bv);
            }
        }
    }
    __syncthreads();
    #pragma unroll
    for (int i = 0; i < 4; ++i) {
        const int e = tid + i * 256;
        const int row = e >> 4, ch = e & 15;
        if (m0 + row < M) {
            const u32x4 v = *reinterpret_cast<const u32x4*>(&sm16[row * 136 + ch * 8]);
            *reinterpret_cast<u32x4*>(C + (size_t)(m0 + row) * N + n0 + ch * 8) = v;
        }
    }
}

// ---------------------------------------------------------------------------
// Merged one-time prep.
// ---------------------------------------------------------------------------
__global__ __launch_bounds__(256) void prep_all(
    const float* __restrict__ vw, const float* __restrict__ bw,
    const float* __restrict__ aw, const float* __restrict__ ow,
    const float* __restrict__ l1, const float* __restrict__ l2,
    const float* __restrict__ bb, const float* __restrict__ ab,
    ushort* __restrict__ dstW, float* __restrict__ dstQB,
    unsigned char* __restrict__ dstW8,
    const float4* __restrict__ src, const float4* __restrict__ pos,
    ushort4* __restrict__ srcb, ushort4* __restrict__ qb)
{
    const int blk = blockIdx.x;
    if (blk < 2817) {
        const int i = blk * 256 + threadIdx.x;
        if (i < 720896) {
            float v;
            if      (i <  65536) v = vw[i];
            else if (i <  98304) v = bw[i -  65536];
            else if (i < 131072) v = aw[i -  98304];
            else if (i < 196608) v = ow[i - 131072];
            else if (i < 458752) v = l1[i - 196608];
            else                 v = l2[i - 458752];
            dstW[i] = f2bu(v);
            if (i >= 458752) dstW8[i - 458752] = (unsigned char)fp8pack1(v);
        } else if (i < 721152) {
            const int j = i - 720896;
            dstQB[j] = (j < 128) ? bb[j] : ab[j - 128];
        }
    } else {
        const int i = (blk - 2817) * 256 + threadIdx.x;
        if (i >= TOKENS * 64) return;
        const float4 s = src[i], p = pos[i];
        ushort4 us, uq;
        us.x = f2bu(s.x); us.y = f2bu(s.y); us.z = f2bu(s.z); us.w = f2bu(s.w);
        uq.x = f2bu(s.x + p.x); uq.y = f2bu(s.y + p.y);
        uq.z = f2bu(s.z + p.z); uq.w = f2bu(s.w + p.w);
        srcb[i] = us; qb[i] = uq;
    }
}

// ---------------------------------------------------------------------------
// Fused box prep + sample v9 (fp8 value, per-head transposed layout).
// valT[(b*8+h)*SLEN + s][32]: x-adjacent corners are CONTIGUOUS 64B -> per
// point only 2 region loads (y0-pair, y1-pair); 4 lanes x dwordx4 cover each
// region. Distinct cachelines/point drop 4 -> ~2.8; useful bytes/line 2x.
// Gathers NONTEMPORAL (no L1 reuse on a 2.88MB random set -> skip the 128B
// L1 fill amplification). Addresses UNCLAMPED; OOB corners weight-0 and read
// in-workspace garbage (valT sits mid-workspace; +-3KB spill is safe).
// ---------------------------------------------------------------------------
__global__ __launch_bounds__(256) void box_fused(
    const unsigned char* __restrict__ val,  // valT fp8
    const ushort* __restrict__ qout,   // (t,256): off[128] | logits[128] bf16
    const float* __restrict__ refw,    // (t,4)
    const float* __restrict__ vratio,  // (B,4,2)
    ushort* __restrict__ attnout)      // (t,256) bf16
{
    __shared__ uint  offs[64 * 17];    // 4,352 B: {short s_y0, short s_y1}
    __shared__ uint2 wts[64 * 17];     // 8,704 B: {pk(w00,w01), pk(w10,w11)}
    const int tid = threadIdx.x;

    // XCD batch partition (bijective for gridDim.x == 2814)
    int work;
    {
        const int x = blockIdx.x & 7, s = blockIdx.x >> 3;
        work = (x < 4) ? (s * 4 + x) : (1408 + s * 4 + (x - 4));
        if ((int)gridDim.x != 2814 || work >= (int)gridDim.x) work = blockIdx.x;
    }
    const int t0 = work * 8;

    // ---------------- phase 1 ----------------
    {
        const int u = tid >> 2, lvl = tid & 3;
        const int t = min(t0 + (u >> 3), TOKENS - 1);
        const int h = u & 7;
        const int b = (t >= SLEN) ? 1 : 0;
        const ushort* qr = qout + (size_t)t * 256;

        const uint2 lu = *reinterpret_cast<const uint2*>(qr + 128 + h * 16 + lvl * 4);
        float e0 = __uint_as_float(lu.x << 16);
        float e1 = __uint_as_float(lu.x & 0xFFFF0000u);
        float e2 = __uint_as_float(lu.y << 16);
        float e3 = __uint_as_float(lu.y & 0xFFFF0000u);
        float mx = fmaxf(fmaxf(e0, e1), fmaxf(e2, e3));
        mx = fmaxf(mx, __shfl_xor(mx, 1));
        mx = fmaxf(mx, __shfl_xor(mx, 2));
        e0 = __expf(e0 - mx); e1 = __expf(e1 - mx);
        e2 = __expf(e2 - mx); e3 = __expf(e3 - mx);
        float ss = e0 + e1 + e2 + e3;
        ss += __shfl_xor(ss, 1);
        ss += __shfl_xor(ss, 2);
        const float inv = 1.f / ss;
        const float pe[4] = { e0 * inv, e1 * inv, e2 * inv, e3 * inv };

        const uint2 ou = *reinterpret_cast<const uint2*>(qr + h * 16 + lvl * 4);
        const float o0 = __uint_as_float(ou.x << 16) * 0.125f;
        const float o1 = __uint_as_float(ou.x & 0xFFFF0000u) * 0.125f;
        const float o2 = __uint_as_float(ou.y << 16) * 0.125f;
        const float o3 = __uint_as_float(ou.y & 0xFFFF0000u) * 0.125f;

        const float4 rw = *reinterpret_cast<const float4*>(refw + (size_t)t * 4);
        const int Ww = (lvl == 0) ? 92 : (lvl == 1) ? 46 : (lvl == 2) ? 23 : 12;
        const int s0 = (lvl == 0) ? 0 : (lvl == 1) ? 8464 : (lvl == 2) ? 10580 : 11109;
        const float vrx = vratio[(b * 4 + lvl) * 2 + 0];
        const float vry = vratio[(b * 4 + lvl) * 2 + 1];

        const float bx  = rw.x + o0 * rw.z;
        const float by  = rw.y + o1 * rw.w;
        const float bwd = fmaxf(rw.z + o2 * rw.z, 0.f);
        const float bhd = fmaxf(rw.w + o3 * rw.w, 0.f);

        #pragma unroll
        for (int k = 0; k < 4; ++k) {
            const float jx = (k & 1) ? 0.25f : -0.25f;
            const float iy = (k & 2) ? 0.25f : -0.25f;
            const float px = (bx + jx * bwd) * vrx * (float)Ww - 0.5f;
            const float py = (by + iy * bhd) * vry * (float)Ww - 0.5f;
            const float x0f = floorf(px), y0f = floorf(py);
            const int x0 = (int)x0f, y0 = (int)y0f;
            const float wx = px - x0f, wy = py - y0f;
            const float wp = pe[k];

            const bool vx0 = (x0 >= 0) && (x0 < Ww);
            const bool vx1 = (x0 + 1 >= 0) && (x0 + 1 < Ww);
            const bool vy0 = (y0 >= 0) && (y0 < Ww);
            const bool vy1 = (y0 + 1 >= 0) && (y0 + 1 < Ww);

            const float w00 = (vx0 && vy0) ? wp * (1.f - wx) * (1.f - wy) : 0.f;
            const float w01 = (vx1 && vy0) ? wp * wx         * (1.f - wy) : 0.f;
            const float w10 = (vx0 && vy1) ? wp * (1.f - wx) * wy         : 0.f;
            const float w11 = (vx1 && vy1) ? wp * wx         * wy         : 0.f;

            const int sy0 = s0 + y0 * Ww + x0;     // unclamped region bases
            const int sy1 = sy0 + Ww;

            const int p = lvl * 4 + k;
            offs[u * 17 + p] = ((uint)(ushort)(short)sy0) |
                               (((uint)(ushort)(short)sy1) << 16);
            wts[u * 17 + p]  = make_uint2(pkf16(w00, w01), pkf16(w10, w11));
        }
    }
    __syncthreads();

    // -------- phase 2: region gathers (2 loads/point, nontemporal) --------
    const int u = tid >> 2, dl = tid & 3;
    const int cx = dl >> 1;          // corner x parity: 0 -> x0, 1 -> x0+1
    const int hd = dl & 1;           // dim half within corner
    const int traw = t0 + (u >> 3);
    const int t = min(traw, TOKENS - 1);
    const int h = u & 7;
    const int b = (t >= SLEN) ? 1 : 0;
    const char* ubase = (const char*)val +
        (size_t)(b * 8 + h) * ((size_t)SLEN * 32) + (uint)dl * 16u;

    const uint*  po = &offs[u * 17];
    const uint2* pw = &wts[u * 17];
    f32x2 ac0 = {0,0}, ac1 = {0,0}, ac2 = {0,0}, ac3 = {0,0};
    f32x2 ac4 = {0,0}, ac5 = {0,0}, ac6 = {0,0}, ac7 = {0,0};

    #pragma unroll
    for (int g = 0; g < 8; ++g) {
        const uint  oA = po[g * 2 + 0];
        const uint  oB = po[g * 2 + 1];
        const uint2 wA = pw[g * 2 + 0];
        const uint2 wB = pw[g * 2 + 1];

        const int sA0 = (short)(oA & 0xFFFFu), sA1 = (short)(oA >> 16);
        const int sB0 = (short)(oB & 0xFFFFu), sB1 = (short)(oB >> 16);

        const u32x4 vA0 = __builtin_nontemporal_load(
            reinterpret_cast<const u32x4*>(ubase + (ptrdiff_t)sA0 * 32));
        const u32x4 vA1 = __builtin_nontemporal_load(
            reinterpret_cast<const u32x4*>(ubase + (ptrdiff_t)sA1 * 32));
        const u32x4 vB0 = __builtin_nontemporal_load(
            reinterpret_cast<const u32x4*>(ubase + (ptrdiff_t)sB0 * 32));
        const u32x4 vB1 = __builtin_nontemporal_load(
            reinterpret_cast<const u32x4*>(ubase + (ptrdiff_t)sB1 * 32));

        const float2 wA0 = __half22float2(*reinterpret_cast<const __half2*>(&wA.x));
        const float2 wA1 = __half22float2(*reinterpret_cast<const __half2*>(&wA.y));
        const float2 wB0 = __half22float2(*reinterpret_cast<const __half2*>(&wB.x));
        const float2 wB1 = __half22float2(*reinterpret_cast<const __half2*>(&wB.y));
        const float fA0 = cx ? wA0.y : wA0.x;
        const float fA1 = cx ? wA1.y : wA1.x;
        const float fB0 = cx ? wB0.y : wB0.x;
        const float fB1 = cx ? wB1.y : wB1.x;

        auto acc16 = [&](const u32x4 v, const float w) {
            f32x2 wv; wv.x = w; wv.y = w;
            ac0 += wv * fp8pair<false>(v[0]);
            ac1 += wv * fp8pair<true >(v[0]);
            ac2 += wv * fp8pair<false>(v[1]);
            ac3 += wv * fp8pair<true >(v[1]);
            ac4 += wv * fp8pair<false>(v[2]);
            ac5 += wv * fp8pair<true >(v[2]);
            ac6 += wv * fp8pair<false>(v[3]);
            ac7 += wv * fp8pair<true >(v[3]);
        };
        acc16(vA0, fA0); acc16(vA1, fA1);
        acc16(vB0, fB0); acc16(vB1, fB1);
    }

    // cross corner combine (lanes differ in bit 1 = cx, same dims by hd)
    auto xsum = [&](f32x2& a) {
        a.x += __shfl_xor(a.x, 2);
        a.y += __shfl_xor(a.y, 2);
    };
    xsum(ac0); xsum(ac1); xsum(ac2); xsum(ac3);
    xsum(ac4); xsum(ac5); xsum(ac6); xsum(ac7);

    if (traw < TOKENS) {
        u32x4 o;
        if (cx == 0) {
            o[0] = (uint)f2bu(ac0.x) | ((uint)f2bu(ac0.y) << 16);
            o[1] = (uint)f2bu(ac1.x) | ((uint)f2bu(ac1.y) << 16);
            o[2] = (uint)f2bu(ac2.x) | ((uint)f2bu(ac2.y) << 16);
            o[3] = (uint)f2bu(ac3.x) | ((uint)f2bu(ac3.y) << 16);
        } else {
            o[0] = (uint)f2bu(ac4.x) | ((uint)f2bu(ac4.y) << 16);
            o[1] = (uint)f2bu(ac5.x) | ((uint)f2bu(ac5.y) << 16);
            o[2] = (uint)f2bu(ac6.x) | ((uint)f2bu(ac6.y) << 16);
            o[3] = (uint)f2bu(ac7.x) | ((uint)f2bu(ac7.y) << 16);
        }
        *reinterpret_cast<u32x4*>(
            attnout + (size_t)t * 256 + h * 32 + hd * 16 + cx * 8) = o;
    }
}

// ---------------------------------------------------------------------------
// LayerNorm(a + b): wave per row, 4 rows/block.
// ---------------------------------------------------------------------------
template<bool AF32, bool OUTF32>
__global__ __launch_bounds__(256) void ln_add2(
    const void* __restrict__ aptr, const ushort* __restrict__ bptr,
    const float* __restrict__ w, const float* __restrict__ bias,
    void* __restrict__ outp, int nrows)
{
    const int lane = threadIdx.x & 63, wv = threadIdx.x >> 6;
    const int row = blockIdx.x * 4 + wv;
    if (row >= nrows) return;
    const size_t base = (size_t)row * 256 + lane * 4;

    float4 av;
    if (AF32) {
        av = *reinterpret_cast<const float4*>((const float*)aptr + base);
    } else {
        const ushort4 u = *reinterpret_cast<const ushort4*>((const ushort*)aptr + base);
        av = make_float4(bu2f(u.x), bu2f(u.y), bu2f(u.z), bu2f(u.w));
    }
    const ushort4 ub = *reinterpret_cast<const ushort4*>(bptr + base);
    const float v0 = av.x + bu2f(ub.x), v1 = av.y + bu2f(ub.y);
    const float v2 = av.z + bu2f(ub.z), v3 = av.w + bu2f(ub.w);

    float s = v0 + v1 + v2 + v3;
    #pragma unroll
    for (int o = 32; o; o >>= 1) s += __shfl_xor(s, o);
    const float mu = s * (1.f / 256.f);
    const float d0 = v0 - mu, d1 = v1 - mu, d2 = v2 - mu, d3 = v3 - mu;
    float s2 = d0 * d0 + d1 * d1 + d2 * d2 + d3 * d3;
    #pragma unroll
    for (int o = 32; o; o >>= 1) s2 += __shfl_xor(s2, o);
    const float rs = rsqrtf(s2 * (1.f / 256.f) + 1e-5f);

    const float4 w4 = *reinterpret_cast<const float4*>(w + lane * 4);
    const float4 g4 = *reinterpret_cast<const float4*>(bias + lane * 4);
    const float r0 = d0 * rs * w4.x + g4.x;
    const float r1 = d1 * rs * w4.y + g4.y;
    const float r2 = d2 * rs * w4.z + g4.z;
    const float r3 = d3 * rs * w4.w + g4.w;
    if (OUTF32) {
        *reinterpret_cast<float4*>((float*)outp + base) = make_float4(r0, r1, r2, r3);
    } else {
        ushort4 u;
        u.x = f2bu(r0); u.y = f2bu(r1); u.z = f2bu(r2); u.w = f2bu(r3);
        *reinterpret_cast<ushort4*>((ushort*)outp + base) = u;
    }
}

// ---------------------------------------------------------------------------
extern "C" void kernel_launch(void* const* d_in, const int* in_sizes, int n_in,
                              void* d_out, int out_size, void* d_ws, size_t ws_size,
                              hipStream_t stream)
{
    const float* src     = (const float*)d_in[0];
    const float* pos     = (const float*)d_in[1];
    const float* vratio  = (const float*)d_in[5];
    const float* refw    = (const float*)d_in[6];
    const float* value_w = (const float*)d_in[7];
    const float* value_b = (const float*)d_in[8];
    const float* out_w   = (const float*)d_in[9];
    const float* out_b   = (const float*)d_in[10];
    const float* box_w   = (const float*)d_in[11];
    const float* box_b   = (const float*)d_in[12];
    const float* attn_w  = (const float*)d_in[13];
    const float* attn_b  = (const float*)d_in[14];
    const float* lin1_w  = (const float*)d_in[15];
    const float* lin1_b  = (const float*)d_in[16];
    const float* lin2_w  = (const float*)d_in[17];
    const float* lin2_b  = (const float*)d_in[18];
    const float* n1w     = (const float*)d_in[19];
    const float* n1b     = (const float*)d_in[20];
    const float* n2w     = (const float*)d_in[21];
    const float* n2b     = (const float*)d_in[22];

    // flat workspace layout (~117 MB of 256 MiB)
    char* wsb = (char*)d_ws;
    ushort* Wb    = (ushort*)(wsb);                  // 1,441,792 B
    float*  qcb   = (float*)(wsb + 1441792);         // 1 KB
    ushort* srcb  = (ushort*)(wsb + 1442816);        // 11.5 MB bf16 src
    ushort* qb    = (ushort*)(wsb + 12965888);       // 11.5 MB bf16 src+pos
    unsigned char* valb = (unsigned char*)(wsb + 24488960);  // 5.76 MB fp8 valT
    ushort* qoutb = (ushort*)(wsb + 36012032);       // 11.5 MB off+logits
    ushort* attb  = (ushort*)(wsb + 47535104);       // 11.5 MB attn out
    ushort* src2b = (ushort*)(wsb + 59058176);       // 11.5 MB src2 bf16
    ushort* xbb   = (ushort*)(wsb + 70581248);       // 11.5 MB x bf16
    unsigned char* hb8 = (unsigned char*)(wsb + 82104320);   // 23.0 MB h fp8
    ushort* yb    = (ushort*)(wsb + 105150464);      // 11.5 MB y bf16
    unsigned char* Wf8 = (unsigned char*)(wsb + 116673536);  // 262,144 B lin2_w fp8

    const dim3 blk(256);

    // one-time prep (weights + input cvt) in a single launch
    prep_all<<<dim3(8444), blk, 0, stream>>>(
        value_w, box_w, attn_w, out_w, lin1_w, lin2_w, box_b, attn_b, Wb, qcb,
        Wf8, (const float4*)src, (const float4*)pos, (ushort4*)srcb, (ushort4*)qb);

    // merged: z=0 value(fp8, per-head transposed) ; z=1 qout
    gemm_small<false, false, 2><<<dim3(352, 2, 2), blk, 0, stream>>>(
        srcb, Wb, value_b, valb,
        qb, Wb + 65536, qcb, qoutb, TOKENS, 256, 256);

    // fused prep + gather (8 tokens/block, transposed fp8 valT)
    box_fused<<<dim3((TOKENS + 7) / 8), blk, 0, stream>>>(
        valb, qoutb, refw, vratio, attb);

    // src2 = attnout @ out_w^T + b -> bf16
    gemm_small<false, false, 0><<<dim3(352, 2, 1), blk, 0, stream>>>(
        attb, Wb + 131072, out_b, src2b,
        attb, Wb + 131072, out_b, src2b, TOKENS, 256, 256);
    // x = LN1(srcb + src2) -> bf16
    ln_add2<false, false><<<dim3((TOKENS + 3) / 4), blk, 0, stream>>>(
        srcb, src2b, n1w, n1b, xbb, TOKENS);
    // h = relu(x @ lin1_w^T + b) -> fp8 row-major (NT streaming stores)
    gemm_small<true, true, 1><<<dim3(352, 8, 1), blk, 0, stream>>>(
        xbb, Wb + 196608, lin1_b, hb8,
        xbb, Wb + 196608, lin1_b, hb8, TOKENS, 1024, 256);
    // y = h(fp8) @ lin2_w(fp8)^T + b -> bf16  [fp8 MFMA]
    gemm_f8<<<dim3(352, 2), blk, 0, stream>>>(
        hb8, Wf8, lin2_b, yb, TOKENS, 256, 1024);
    // out = LN2(x + y) -> f32
    ln_add2<false, true><<<dim3((TOKENS + 3) / 4), blk, 0, stream>>>(
        xbb, yb, n2w, n2b, (float*)d_out, TOKENS);
}

// Round 21
// 130.370 us; speedup vs baseline: 1.2776x; 1.2776x over previous
//
#include <hip/hip_runtime.h>
#include <hip/hip_bf16.h>
#include <hip/hip_fp16.h>

#define TOKENS 22506
#define SLEN   11253

typedef __bf16 bf16x8 __attribute__((ext_vector_type(8)));
typedef float  f32x4  __attribute__((ext_vector_type(4)));
typedef float  f32x2  __attribute__((ext_vector_type(2)));
typedef uint   u32x4  __attribute__((ext_vector_type(4)));
typedef uint   u32x2  __attribute__((ext_vector_type(2)));

#if defined(__has_builtin)
#if __has_builtin(__builtin_amdgcn_cvt_pk_f32_fp8) && __has_builtin(__builtin_amdgcn_cvt_pk_fp8_f32)
#define HAS_FP8CVT 1
#endif
#endif

__device__ __forceinline__ ushort f2bu(float f) {
    __hip_bfloat16 h = __float2bfloat16(f);   // RNE
    return *reinterpret_cast<ushort*>(&h);
}
__device__ __forceinline__ float bu2f(ushort u) {
    return __uint_as_float((uint)u << 16);
}
__device__ __forceinline__ uint pkf16(float a, float b) {
    __half2 h = __floats2half2_rn(a, b);
    return *reinterpret_cast<uint*>(&h);
}
__device__ __forceinline__ void gl16(const void* g, void* l) {
    __builtin_amdgcn_global_load_lds(
        (__attribute__((address_space(1))) void*)(g),
        (__attribute__((address_space(3))) void*)(l), 16, 0, 0);
}

#ifndef HAS_FP8CVT
// fallback software e4m3fn codec (compile-safety only)
__device__ __forceinline__ uint enc_fp8(float x) {
    if (!(fabsf(x) >= 0.f)) return 0;
    uint u = __float_as_uint(x);
    uint s = (u >> 24) & 0x80u;
    float ax = fabsf(x);
    if (ax >= 448.f) return s | 0x7Eu;
    if (ax < 0.0009765625f) return s;
    int e; frexpf(ax, &e);
    int ue = e - 1;
    if (ue < -6) {
        int m = (int)(ax * 512.f + 0.5f);
        if (m > 7) m = 7;
        return s | (uint)m;
    }
    float q = ax * exp2f((float)(3 - ue));
    int mi = (int)(q + 0.5f);
    if (mi >= 16) { mi >>= 1; ++ue; if (ue > 8) return s | 0x7Eu; }
    return s | ((uint)(ue + 7) << 3) | ((uint)mi & 7u);
}
__device__ __forceinline__ float dec_fp8(uint b) {
    const float sgn = (b & 0x80u) ? -1.f : 1.f;
    const uint e = (b >> 3) & 15u, m = b & 7u;
    if (e == 0) return sgn * (float)m * 0.001953125f;
    return sgn * (1.0f + (float)m * 0.125f) * exp2f((float)e - 7.f);
}
#endif

__device__ __forceinline__ uint fp8pack4(float f0, float f1, float f2, float f3) {
#ifdef HAS_FP8CVT
    int p = 0;
    p = __builtin_amdgcn_cvt_pk_fp8_f32(f0, f1, p, false);
    p = __builtin_amdgcn_cvt_pk_fp8_f32(f2, f3, p, true);
    return (uint)p;
#else
    return enc_fp8(f0) | (enc_fp8(f1) << 8) | (enc_fp8(f2) << 16) | (enc_fp8(f3) << 24);
#endif
}
__device__ __forceinline__ uint fp8pack1(float f) {
#ifdef HAS_FP8CVT
    return (uint)__builtin_amdgcn_cvt_pk_fp8_f32(f, f, 0, false) & 0xFFu;
#else
    return enc_fp8(f);
#endif
}
template<bool HI>
__device__ __forceinline__ f32x2 fp8pair(uint w) {
#ifdef HAS_FP8CVT
    auto c = __builtin_amdgcn_cvt_pk_f32_fp8((int)w, HI);   // HI is a literal
    f32x2 r; r.x = c[0]; r.y = c[1]; return r;
#else
    const uint sh = HI ? 16u : 0u;
    f32x2 r; r.x = dec_fp8((w >> sh) & 0xFFu); r.y = dec_fp8((w >> (sh + 8)) & 0xFFu);
    return r;
#endif
}

// XCD row-partition swizzle (bijective when nx % 8 == 0); perf heuristic.
__device__ __forceinline__ void xcd_swz(int& bx, int& by) {
    const int nx = gridDim.x, ny = gridDim.y;
    if ((nx & 7) == 0) {
        const int L = blockIdx.x + nx * blockIdx.y;
        const int chunk = nx >> 3;
        const int k = L & 7, j = L >> 3;
        bx = k * chunk + (j % chunk);
        by = j / chunk;
        if (by >= ny) { bx = blockIdx.x; by = blockIdx.y; }  // safety
    } else {
        bx = blockIdx.x; by = blockIdx.y;
    }
}

// ---------------------------------------------------------------------------
// 64x128-tile MFMA GEMM (bf16 inputs).
// ---------------------------------------------------------------------------
template<bool RELU, bool NTSTORE, bool F8Z0>
__global__ __launch_bounds__(256) void gemm_small(
    const ushort* __restrict__ A0, const ushort* __restrict__ W0,
    const float* __restrict__ b0, void* __restrict__ C0,
    const ushort* __restrict__ A1, const ushort* __restrict__ W1,
    const float* __restrict__ b1, void* __restrict__ C1,
    int M, int N, int K)
{
    const bool zz = blockIdx.z != 0;
    const ushort* A   = zz ? A1 : A0;
    const ushort* W   = zz ? W1 : W0;
    const float* bias = zz ? b1 : b0;
    void* Cptr        = zz ? C1 : C0;

    __shared__ ushort smem[12288];           // 24 KB
    const int tid  = threadIdx.x;
    const int lane = tid & 63;
    const int wid  = tid >> 6;
    const int wr = wid >> 1, wc = wid & 1;
    int bx, by; xcd_swz(bx, by);
    const int m0 = bx * 64, n0 = by * 128;
    const int lrow = lane & 15, lhi = lane >> 4;

    const int arow = tid >> 2;               // 0..63
    const int scol = (tid & 3) << 3;
    const ushort* ga  = A + (size_t)min(m0 + arow, M - 1) * K + scol;
    const ushort* gb0 = W + (size_t)(n0 + arow)      * K + scol;
    const ushort* gb1 = W + (size_t)(n0 + arow + 64) * K + scol;

    f32x4 acc[2][4] = {};
    const int NT = K >> 5;

    gl16(ga,  &smem[tid * 8]);
    gl16(gb0, &smem[4096 + tid * 8]);
    gl16(gb1, &smem[4096 + tid * 8 + 2048]);

    int cur = 0;
    for (int t = 0; t < NT; ++t) {
        __syncthreads();
        if (t + 1 < NT) {
            const int k0 = (t + 1) << 5;
            const int nb = cur ^ 1;
            gl16(ga  + k0, &smem[nb * 2048 + tid * 8]);
            gl16(gb0 + k0, &smem[4096 + nb * 4096 + tid * 8]);
            gl16(gb1 + k0, &smem[4096 + nb * 4096 + tid * 8 + 2048]);
        }
        bf16x8 afr[2], bfr[4];
        #pragma unroll
        for (int m = 0; m < 2; ++m)
            afr[m] = *reinterpret_cast<const bf16x8*>(
                &smem[cur * 2048 + (wr * 32 + m * 16 + lrow) * 32 + lhi * 8]);
        #pragma unroll
        for (int n = 0; n < 4; ++n)
            bfr[n] = *reinterpret_cast<const bf16x8*>(
                &smem[4096 + cur * 4096 + (wc * 64 + n * 16 + lrow) * 32 + lhi * 8]);
        #pragma unroll
        for (int m = 0; m < 2; ++m)
            #pragma unroll
            for (int n = 0; n < 4; ++n)
                acc[m][n] = __builtin_amdgcn_mfma_f32_16x16x32_bf16(
                    afr[m], bfr[n], acc[m][n], 0, 0, 0);
        cur ^= 1;
    }

    // epilogue: regs -> LDS (padded 136-elem rows) -> coalesced stores
    __syncthreads();
    #pragma unroll
    for (int m = 0; m < 2; ++m) {
        #pragma unroll
        for (int n = 0; n < 4; ++n) {
            const int col = wc * 64 + n * 16 + lrow;
            const float bv = bias[n0 + col];
            #pragma unroll
            for (int r = 0; r < 4; ++r) {
                const int row = wr * 32 + m * 16 + lhi * 4 + r;
                float v = acc[m][n][r] + bv;
                if (RELU) v = fmaxf(v, 0.f);
                smem[row * 136 + col] = f2bu(v);
            }
        }
    }
    __syncthreads();
    if (F8Z0 && !zz) {
        #pragma unroll
        for (int i = 0; i < 4; ++i) {
            const int e = tid + i * 256;
            const int row = e >> 4, ch = e & 15;
            if (m0 + row < M) {
                const u32x4 v = *reinterpret_cast<const u32x4*>(&smem[row * 136 + ch * 8]);
                float f[8];
                #pragma unroll
                for (int j = 0; j < 4; ++j) {
                    f[2 * j]     = __uint_as_float(v[j] << 16);
                    f[2 * j + 1] = __uint_as_float(v[j] & 0xFFFF0000u);
                }
                u32x2 o;
                o[0] = fp8pack4(f[0], f[1], f[2], f[3]);
                o[1] = fp8pack4(f[4], f[5], f[6], f[7]);
                u32x2* dst = reinterpret_cast<u32x2*>(
                    (unsigned char*)Cptr + (size_t)(m0 + row) * N + n0 + ch * 8);
                if (NTSTORE) __builtin_nontemporal_store(o, dst);
                else *dst = o;
            }
        }
    } else {
        #pragma unroll
        for (int i = 0; i < 4; ++i) {
            const int e = tid + i * 256;
            const int row = e >> 4, ch = e & 15;
            if (m0 + row < M) {
                const u32x4 v = *reinterpret_cast<const u32x4*>(&smem[row * 136 + ch * 8]);
                u32x4* dst = reinterpret_cast<u32x4*>(
                    (ushort*)Cptr + (size_t)(m0 + row) * N + n0 + ch * 8);
                if (NTSTORE) __builtin_nontemporal_store(v, dst);
                else *dst = v;
            }
        }
    }
}

// ---------------------------------------------------------------------------
// 64x128-tile MFMA GEMM, fp8-e4m3 A and W (lin2).
// ---------------------------------------------------------------------------
__global__ __launch_bounds__(256) void gemm_f8(
    const unsigned char* __restrict__ A, const unsigned char* __restrict__ W,
    const float* __restrict__ bias, ushort* __restrict__ C,
    int M, int N, int K)
{
    __shared__ unsigned char smem[17408];    // staging 12 KB; epilogue 17.4 KB
    const int tid  = threadIdx.x;
    const int lane = tid & 63;
    const int wid  = tid >> 6;
    const int wr = wid >> 1, wc = wid & 1;
    int bx, by; xcd_swz(bx, by);
    const int m0 = bx * 64, n0 = by * 128;
    const int lrow = lane & 15, lhi = lane >> 4;

    const int arow = tid >> 1;               // 0..127
    const int achk = (tid & 1) << 4;         // 0 or 16 (bytes)
    const unsigned char* ga = A + (size_t)min(m0 + (arow & 63), M - 1) * K + achk;
    const unsigned char* gb = W + (size_t)(n0 + arow) * K + achk;

    f32x4 acc[2][4] = {};
    const int NT = K >> 5;

    if (tid < 128) gl16(ga, &smem[tid * 16]);
    gl16(gb, &smem[4096 + tid * 16]);

    int cur = 0;
    for (int t = 0; t < NT; ++t) {
        __syncthreads();
        if (t + 1 < NT) {
            const int k0 = (t + 1) << 5;
            const int nb = cur ^ 1;
            if (tid < 128) gl16(ga + k0, &smem[nb * 2048 + tid * 16]);
            gl16(gb + k0, &smem[4096 + nb * 4096 + tid * 16]);
        }
        long afr[2], bfr[4];
        #pragma unroll
        for (int m = 0; m < 2; ++m)
            afr[m] = *reinterpret_cast<const long*>(
                &smem[cur * 2048 + (wr * 32 + m * 16 + lrow) * 32 + lhi * 8]);
        #pragma unroll
        for (int n = 0; n < 4; ++n)
            bfr[n] = *reinterpret_cast<const long*>(
                &smem[4096 + cur * 4096 + (wc * 64 + n * 16 + lrow) * 32 + lhi * 8]);
        #pragma unroll
        for (int m = 0; m < 2; ++m)
            #pragma unroll
            for (int n = 0; n < 4; ++n)
                acc[m][n] = __builtin_amdgcn_mfma_f32_16x16x32_fp8_fp8(
                    afr[m], bfr[n], acc[m][n], 0, 0, 0);
        cur ^= 1;
    }

    __syncthreads();
    ushort* sm16 = reinterpret_cast<ushort*>(smem);
    #pragma unroll
    for (int m = 0; m < 2; ++m) {
        #pragma unroll
        for (int n = 0; n < 4; ++n) {
            const int col = wc * 64 + n * 16 + lrow;
            const float bv = bias[n0 + col];
            #pragma unroll
            for (int r = 0; r < 4; ++r) {
                const int row = wr * 32 + m * 16 + lhi * 4 + r;
                sm16[row * 136 + col] = f2bu(acc[m][n][r] + bv);
            }
        }
    }
    __syncthreads();
    #pragma unroll
    for (int i = 0; i < 4; ++i) {
        const int e = tid + i * 256;
        const int row = e >> 4, ch = e & 15;
        if (m0 + row < M) {
            const u32x4 v = *reinterpret_cast<const u32x4*>(&sm16[row * 136 + ch * 8]);
            *reinterpret_cast<u32x4*>(C + (size_t)(m0 + row) * N + n0 + ch * 8) = v;
        }
    }
}

// ---------------------------------------------------------------------------
// Merged one-time prep.
// ---------------------------------------------------------------------------
__global__ __launch_bounds__(256) void prep_all(
    const float* __restrict__ vw, const float* __restrict__ bw,
    const float* __restrict__ aw, const float* __restrict__ ow,
    const float* __restrict__ l1, const float* __restrict__ l2,
    const float* __restrict__ bb, const float* __restrict__ ab,
    ushort* __restrict__ dstW, float* __restrict__ dstQB,
    unsigned char* __restrict__ dstW8,
    const float4* __restrict__ src, const float4* __restrict__ pos,
    ushort4* __restrict__ srcb, ushort4* __restrict__ qb)
{
    const int blk = blockIdx.x;
    if (blk < 2817) {
        const int i = blk * 256 + threadIdx.x;
        if (i < 720896) {
            float v;
            if      (i <  65536) v = vw[i];
            else if (i <  98304) v = bw[i -  65536];
            else if (i < 131072) v = aw[i -  98304];
            else if (i < 196608) v = ow[i - 131072];
            else if (i < 458752) v = l1[i - 196608];
            else                 v = l2[i - 458752];
            dstW[i] = f2bu(v);
            if (i >= 458752) dstW8[i - 458752] = (unsigned char)fp8pack1(v);
        } else if (i < 721152) {
            const int j = i - 720896;
            dstQB[j] = (j < 128) ? bb[j] : ab[j - 128];
        }
    } else {
        const int i = (blk - 2817) * 256 + threadIdx.x;
        if (i >= TOKENS * 64) return;
        const float4 s = src[i], p = pos[i];
        ushort4 us, uq;
        us.x = f2bu(s.x); us.y = f2bu(s.y); us.z = f2bu(s.z); us.w = f2bu(s.w);
        uq.x = f2bu(s.x + p.x); uq.y = f2bu(s.y + p.y);
        uq.z = f2bu(s.z + p.z); uq.w = f2bu(s.w + p.w);
        srcb[i] = us; qb[i] = uq;
    }
}

// ---------------------------------------------------------------------------
// Fused box prep + sample v8 (fp8 value). Block = 8 tokens (64 units).
// Phase 2 corner-split: lane = (unit, dim-half hd, corner-pair cp). Per point
// each lane issues 2x dwordx4 (its pair's corner rows at its 16-dim half).
// Final cross-pair combine: shfl_xor(2) sum; lane writes its 8-dim slice.
// ---------------------------------------------------------------------------
__global__ __launch_bounds__(256) void box_fused(
    const unsigned char* __restrict__ val,  // (B*SLEN, 256) fp8
    const ushort* __restrict__ qout,   // (t,256): off[128] | logits[128] bf16
    const float* __restrict__ refw,    // (t,4)
    const float* __restrict__ vratio,  // (B,4,2)
    ushort* __restrict__ attnout)      // (t,256) bf16
{
    __shared__ ushort4 offs[64 * 17];  // 8,704 B
    __shared__ uint2 wts[64 * 17];     // 8,704 B
    const int tid = threadIdx.x;

    // XCD batch partition (bijective for gridDim.x == 2814)
    int work;
    {
        const int x = blockIdx.x & 7, s = blockIdx.x >> 3;
        work = (x < 4) ? (s * 4 + x) : (1408 + s * 4 + (x - 4));
        if ((int)gridDim.x != 2814 || work >= (int)gridDim.x) work = blockIdx.x;
    }
    const int t0 = work * 8;

    // ---------------- phase 1 ----------------
    {
        const int u = tid >> 2, lvl = tid & 3;
        const int t = min(t0 + (u >> 3), TOKENS - 1);
        const int h = u & 7;
        const int b = (t >= SLEN) ? 1 : 0;
        const ushort* qr = qout + (size_t)t * 256;

        const uint2 lu = *reinterpret_cast<const uint2*>(qr + 128 + h * 16 + lvl * 4);
        float e0 = __uint_as_float(lu.x << 16);
        float e1 = __uint_as_float(lu.x & 0xFFFF0000u);
        float e2 = __uint_as_float(lu.y << 16);
        float e3 = __uint_as_float(lu.y & 0xFFFF0000u);
        float mx = fmaxf(fmaxf(e0, e1), fmaxf(e2, e3));
        mx = fmaxf(mx, __shfl_xor(mx, 1));
        mx = fmaxf(mx, __shfl_xor(mx, 2));
        e0 = __expf(e0 - mx); e1 = __expf(e1 - mx);
        e2 = __expf(e2 - mx); e3 = __expf(e3 - mx);
        float ss = e0 + e1 + e2 + e3;
        ss += __shfl_xor(ss, 1);
        ss += __shfl_xor(ss, 2);
        const float inv = 1.f / ss;
        const float pe[4] = { e0 * inv, e1 * inv, e2 * inv, e3 * inv };

        const uint2 ou = *reinterpret_cast<const uint2*>(qr + h * 16 + lvl * 4);
        const float o0 = __uint_as_float(ou.x << 16) * 0.125f;
        const float o1 = __uint_as_float(ou.x & 0xFFFF0000u) * 0.125f;
        const float o2 = __uint_as_float(ou.y << 16) * 0.125f;
        const float o3 = __uint_as_float(ou.y & 0xFFFF0000u) * 0.125f;

        const float4 rw = *reinterpret_cast<const float4*>(refw + (size_t)t * 4);
        const int Ww = (lvl == 0) ? 92 : (lvl == 1) ? 46 : (lvl == 2) ? 23 : 12;
        const int s0 = (lvl == 0) ? 0 : (lvl == 1) ? 8464 : (lvl == 2) ? 10580 : 11109;
        const float vrx = vratio[(b * 4 + lvl) * 2 + 0];
        const float vry = vratio[(b * 4 + lvl) * 2 + 1];

        const float bx  = rw.x + o0 * rw.z;
        const float by  = rw.y + o1 * rw.w;
        const float bwd = fmaxf(rw.z + o2 * rw.z, 0.f);
        const float bhd = fmaxf(rw.w + o3 * rw.w, 0.f);

        #pragma unroll
        for (int k = 0; k < 4; ++k) {
            const float jx = (k & 1) ? 0.25f : -0.25f;
            const float iy = (k & 2) ? 0.25f : -0.25f;
            const float px = (bx + jx * bwd) * vrx * (float)Ww - 0.5f;
            const float py = (by + iy * bhd) * vry * (float)Ww - 0.5f;
            const float x0f = floorf(px), y0f = floorf(py);
            const int x0 = (int)x0f, y0 = (int)y0f;
            const float wx = px - x0f, wy = py - y0f;
            const float wp = pe[k];

            const bool vx0 = (x0 >= 0) && (x0 < Ww);
            const bool vx1 = (x0 + 1 >= 0) && (x0 + 1 < Ww);
            const bool vy0 = (y0 >= 0) && (y0 < Ww);
            const bool vy1 = (y0 + 1 >= 0) && (y0 + 1 < Ww);
            const int cx0 = min(max(x0, 0), Ww - 1);
            const int cx1 = min(max(x0 + 1, 0), Ww - 1);
            const int cy0 = min(max(y0, 0), Ww - 1);
            const int cy1 = min(max(y0 + 1, 0), Ww - 1);

            const float w00 = (vx0 && vy0) ? wp * (1.f - wx) * (1.f - wy) : 0.f;
            const float w01 = (vx1 && vy0) ? wp * wx         * (1.f - wy) : 0.f;
            const float w10 = (vx0 && vy1) ? wp * (1.f - wx) * wy         : 0.f;
            const float w11 = (vx1 && vy1) ? wp * wx         * wy         : 0.f;

            ushort4 sp;
            sp.x = (ushort)(s0 + cy0 * Ww + cx0);
            sp.y = (ushort)(s0 + cy0 * Ww + cx1);
            sp.z = (ushort)(s0 + cy1 * Ww + cx0);
            sp.w = (ushort)(s0 + cy1 * Ww + cx1);

            const int p = lvl * 4 + k;
            offs[u * 17 + p] = sp;
            wts[u * 17 + p]  = make_uint2(pkf16(w00, w01), pkf16(w10, w11));
        }
    }
    __syncthreads();

    // -------- phase 2: corner-split dwordx4 (2 loads/point/lane) --------
    const int u = tid >> 2, dl = tid & 3;
    const int hd = dl & 1;          // dim half: 0 -> dims 0-15, 1 -> 16-31
    const int cp = dl >> 1;         // corner pair: 0 -> {c0,c1}, 1 -> {c2,c3}
    const int traw = t0 + (u >> 3);
    const int t = min(traw, TOKENS - 1);
    const int h = u & 7;
    const uint boff = ((t >= SLEN) ? (uint)SLEN * 256u : 0u)
                    + (uint)h * 32u + (uint)hd * 16u;
    const char* base = (const char*)val;

    const ushort4* po = &offs[u * 17];
    const uint2* pw = &wts[u * 17];
    f32x2 ac0 = {0,0}, ac1 = {0,0}, ac2 = {0,0}, ac3 = {0,0};
    f32x2 ac4 = {0,0}, ac5 = {0,0}, ac6 = {0,0}, ac7 = {0,0};

    #pragma unroll
    for (int g = 0; g < 8; ++g) {
        const ushort4 spA = po[g * 2 + 0];
        const ushort4 spB = po[g * 2 + 1];
        const uint2  wA  = pw[g * 2 + 0];
        const uint2  wB  = pw[g * 2 + 1];

        const uint rA0 = cp ? (uint)spA.z : (uint)spA.x;
        const uint rA1 = cp ? (uint)spA.w : (uint)spA.y;
        const uint rB0 = cp ? (uint)spB.z : (uint)spB.x;
        const uint rB1 = cp ? (uint)spB.w : (uint)spB.y;

        const u32x4 vA0 = *reinterpret_cast<const u32x4*>(base + ((rA0 << 8) + boff));
        const u32x4 vA1 = *reinterpret_cast<const u32x4*>(base + ((rA1 << 8) + boff));
        const u32x4 vB0 = *reinterpret_cast<const u32x4*>(base + ((rB0 << 8) + boff));
        const u32x4 vB1 = *reinterpret_cast<const u32x4*>(base + ((rB1 << 8) + boff));

        const uint wAu = cp ? wA.y : wA.x;
        const uint wBu = cp ? wB.y : wB.x;
        const float2 wAf = __half22float2(*reinterpret_cast<const __half2*>(&wAu));
        const float2 wBf = __half22float2(*reinterpret_cast<const __half2*>(&wBu));

        auto acc16 = [&](const u32x4 v, const float w) {
            f32x2 wv; wv.x = w; wv.y = w;
            ac0 += wv * fp8pair<false>(v[0]);
            ac1 += wv * fp8pair<true >(v[0]);
            ac2 += wv * fp8pair<false>(v[1]);
            ac3 += wv * fp8pair<true >(v[1]);
            ac4 += wv * fp8pair<false>(v[2]);
            ac5 += wv * fp8pair<true >(v[2]);
            ac6 += wv * fp8pair<false>(v[3]);
            ac7 += wv * fp8pair<true >(v[3]);
        };
        acc16(vA0, wAf.x); acc16(vA1, wAf.y);
        acc16(vB0, wBf.x); acc16(vB1, wBf.y);
    }

    // cross corner-pair combine (lanes differ in bit 1 = cp, same dims by hd)
    auto xsum = [&](f32x2& a) {
        a.x += __shfl_xor(a.x, 2);
        a.y += __shfl_xor(a.y, 2);
    };
    xsum(ac0); xsum(ac1); xsum(ac2); xsum(ac3);
    xsum(ac4); xsum(ac5); xsum(ac6); xsum(ac7);

    if (traw < TOKENS) {
        u32x4 o;
        if (cp == 0) {
            o[0] = (uint)f2bu(ac0.x) | ((uint)f2bu(ac0.y) << 16);
            o[1] = (uint)f2bu(ac1.x) | ((uint)f2bu(ac1.y) << 16);
            o[2] = (uint)f2bu(ac2.x) | ((uint)f2bu(ac2.y) << 16);
            o[3] = (uint)f2bu(ac3.x) | ((uint)f2bu(ac3.y) << 16);
        } else {
            o[0] = (uint)f2bu(ac4.x) | ((uint)f2bu(ac4.y) << 16);
            o[1] = (uint)f2bu(ac5.x) | ((uint)f2bu(ac5.y) << 16);
            o[2] = (uint)f2bu(ac6.x) | ((uint)f2bu(ac6.y) << 16);
            o[3] = (uint)f2bu(ac7.x) | ((uint)f2bu(ac7.y) << 16);
        }
        *reinterpret_cast<u32x4*>(
            attnout + (size_t)t * 256 + h * 32 + hd * 16 + cp * 8) = o;
    }
}

// ---------------------------------------------------------------------------
// LayerNorm(a + b): wave per row, 4 rows/block.
// ---------------------------------------------------------------------------
template<bool AF32, bool OUTF32>
__global__ __launch_bounds__(256) void ln_add2(
    const void* __restrict__ aptr, const ushort* __restrict__ bptr,
    const float* __restrict__ w, const float* __restrict__ bias,
    void* __restrict__ outp, int nrows)
{
    const int lane = threadIdx.x & 63, wv = threadIdx.x >> 6;
    const int row = blockIdx.x * 4 + wv;
    if (row >= nrows) return;
    const size_t base = (size_t)row * 256 + lane * 4;

    float4 av;
    if (AF32) {
        av = *reinterpret_cast<const float4*>((const float*)aptr + base);
    } else {
        const ushort4 u = *reinterpret_cast<const ushort4*>((const ushort*)aptr + base);
        av = make_float4(bu2f(u.x), bu2f(u.y), bu2f(u.z), bu2f(u.w));
    }
    const ushort4 ub = *reinterpret_cast<const ushort4*>(bptr + base);
    const float v0 = av.x + bu2f(ub.x), v1 = av.y + bu2f(ub.y);
    const float v2 = av.z + bu2f(ub.z), v3 = av.w + bu2f(ub.w);

    float s = v0 + v1 + v2 + v3;
    #pragma unroll
    for (int o = 32; o; o >>= 1) s += __shfl_xor(s, o);
    const float mu = s * (1.f / 256.f);
    const float d0 = v0 - mu, d1 = v1 - mu, d2 = v2 - mu, d3 = v3 - mu;
    float s2 = d0 * d0 + d1 * d1 + d2 * d2 + d3 * d3;
    #pragma unroll
    for (int o = 32; o; o >>= 1) s2 += __shfl_xor(s2, o);
    const float rs = rsqrtf(s2 * (1.f / 256.f) + 1e-5f);

    const float4 w4 = *reinterpret_cast<const float4*>(w + lane * 4);
    const float4 g4 = *reinterpret_cast<const float4*>(bias + lane * 4);
    const float r0 = d0 * rs * w4.x + g4.x;
    const float r1 = d1 * rs * w4.y + g4.y;
    const float r2 = d2 * rs * w4.z + g4.z;
    const float r3 = d3 * rs * w4.w + g4.w;
    if (OUTF32) {
        *reinterpret_cast<float4*>((float*)outp + base) = make_float4(r0, r1, r2, r3);
    } else {
        ushort4 u;
        u.x = f2bu(r0); u.y = f2bu(r1); u.z = f2bu(r2); u.w = f2bu(r3);
        *reinterpret_cast<ushort4*>((ushort*)outp + base) = u;
    }
}

// ---------------------------------------------------------------------------
extern "C" void kernel_launch(void* const* d_in, const int* in_sizes, int n_in,
                              void* d_out, int out_size, void* d_ws, size_t ws_size,
                              hipStream_t stream)
{
    const float* src     = (const float*)d_in[0];
    const float* pos     = (const float*)d_in[1];
    const float* vratio  = (const float*)d_in[5];
    const float* refw    = (const float*)d_in[6];
    const float* value_w = (const float*)d_in[7];
    const float* value_b = (const float*)d_in[8];
    const float* out_w   = (const float*)d_in[9];
    const float* out_b   = (const float*)d_in[10];
    const float* box_w   = (const float*)d_in[11];
    const float* box_b   = (const float*)d_in[12];
    const float* attn_w  = (const float*)d_in[13];
    const float* attn_b  = (const float*)d_in[14];
    const float* lin1_w  = (const float*)d_in[15];
    const float* lin1_b  = (const float*)d_in[16];
    const float* lin2_w  = (const float*)d_in[17];
    const float* lin2_b  = (const float*)d_in[18];
    const float* n1w     = (const float*)d_in[19];
    const float* n1b     = (const float*)d_in[20];
    const float* n2w     = (const float*)d_in[21];
    const float* n2b     = (const float*)d_in[22];

    // flat workspace layout (~117 MB of 256 MiB)
    char* wsb = (char*)d_ws;
    ushort* Wb    = (ushort*)(wsb);                  // 1,441,792 B
    float*  qcb   = (float*)(wsb + 1441792);         // 1 KB
    ushort* srcb  = (ushort*)(wsb + 1442816);        // 11.5 MB bf16 src
    ushort* qb    = (ushort*)(wsb + 12965888);       // 11.5 MB bf16 src+pos
    unsigned char* valb = (unsigned char*)(wsb + 24488960);  // 5.76 MB fp8 value
    ushort* qoutb = (ushort*)(wsb + 36012032);       // 11.5 MB off+logits
    ushort* attb  = (ushort*)(wsb + 47535104);       // 11.5 MB attn out
    ushort* src2b = (ushort*)(wsb + 59058176);       // 11.5 MB src2 bf16
    ushort* xbb   = (ushort*)(wsb + 70581248);       // 11.5 MB x bf16
    unsigned char* hb8 = (unsigned char*)(wsb + 82104320);   // 23.0 MB h fp8
    ushort* yb    = (ushort*)(wsb + 105150464);      // 11.5 MB y bf16
    unsigned char* Wf8 = (unsigned char*)(wsb + 116673536);  // 262,144 B lin2_w fp8

    const dim3 blk(256);

    // one-time prep (weights + input cvt) in a single launch
    prep_all<<<dim3(8444), blk, 0, stream>>>(
        value_w, box_w, attn_w, out_w, lin1_w, lin2_w, box_b, attn_b, Wb, qcb,
        Wf8, (const float4*)src, (const float4*)pos, (ushort4*)srcb, (ushort4*)qb);

    // merged: z=0 value(fp8) = src @ value_w^T ; z=1 qout = q @ [box;attn]^T
    gemm_small<false, false, true><<<dim3(352, 2, 2), blk, 0, stream>>>(
        srcb, Wb, value_b, valb,
        qb, Wb + 65536, qcb, qoutb, TOKENS, 256, 256);

    // fused prep + gather (8 tokens/block, fp8 value, XCD batch partition)
    box_fused<<<dim3((TOKENS + 7) / 8), blk, 0, stream>>>(
        valb, qoutb, refw, vratio, attb);

    // src2 = attnout @ out_w^T + b -> bf16
    gemm_small<false, false, false><<<dim3(352, 2, 1), blk, 0, stream>>>(
        attb, Wb + 131072, out_b, src2b,
        attb, Wb + 131072, out_b, src2b, TOKENS, 256, 256);
    // x = LN1(srcb + src2) -> bf16
    ln_add2<false, false><<<dim3((TOKENS + 3) / 4), blk, 0, stream>>>(
        srcb, src2b, n1w, n1b, xbb, TOKENS);
    // h = relu(x @ lin1_w^T + b) -> fp8 (NT streaming stores)
    gemm_small<true, true, true><<<dim3(352, 8, 1), blk, 0, stream>>>(
        xbb, Wb + 196608, lin1_b, hb8,
        xbb, Wb + 196608, lin1_b, hb8, TOKENS, 1024, 256);
    // y = h(fp8) @ lin2_w(fp8)^T + b -> bf16  [fp8 MFMA]
    gemm_f8<<<dim3(352, 2), blk, 0, stream>>>(
        hb8, Wf8, lin2_b, yb, TOKENS, 256, 1024);
    // out = LN2(x + y) -> f32
    ln_add2<false, true><<<dim3((TOKENS + 3) / 4), blk, 0, stream>>>(
        xbb, yb, n2w, n2b, (float*)d_out, TOKENS);
}